// Round 15
// baseline (209.605 us; speedup 1.0000x reference)
//
#include <hip/hip_runtime.h>
#include <hip/hip_bf16.h>
#include <math.h>

#define B_ 2
#define S_ 2048
#define D_ 1024
#define H_ 4
#define DK_ 256
#define NJ 24
#define NG 96
#define KT2 256
#define NTL2 ((S_ / 2) / KT2)   // 4 iters per half

typedef _Float16 f16;
typedef _Float16 f16x2 __attribute__((ext_vector_type(2)));
typedef _Float16 f16x4 __attribute__((ext_vector_type(4)));
typedef _Float16 f16x8 __attribute__((ext_vector_type(8)));
typedef float f32x16 __attribute__((ext_vector_type(16)));
typedef float v2f __attribute__((ext_vector_type(2)));

// ---------------- fold Wq into proj -> f16 Mf[hj][d] ----------------
__global__ __launch_bounds__(256) void k_fuse(const float* __restrict__ Wq_w,
                                              const float* __restrict__ proj_w,
                                              f16* __restrict__ Mf) {
  int tid = blockIdx.x * 256 + threadIdx.x;
  int hj = tid >> 10;
  int d = tid & 1023;
  int h = hj / NJ, j = hj - h * NJ;
  const float* wq = Wq_w + (size_t)(h * DK_) * D_ + d;
  const float* pw = proj_w + j * DK_;
  float acc = 0.f;
#pragma unroll 8
  for (int k = 0; k < DK_; ++k) acc += wq[(size_t)k * D_] * pw[k];
  Mf[(size_t)hj * D_ + d] = (f16)acc;
}

__global__ void k_fuse_bias(const float* __restrict__ Wq_b,
                            const float* __restrict__ proj_w,
                            const float* __restrict__ proj_b,
                            float* __restrict__ cbias,
                            float* __restrict__ pbias) {
  int hj = threadIdx.x;
  if (hj < NG) {
    int h = hj / NJ, j = hj - h * NJ;
    float acc = proj_b[j];
    for (int k = 0; k < DK_; ++k) acc += Wq_b[h * DK_ + k] * proj_w[j * DK_ + k];
    cbias[hj] = acc;
    pbias[hj] = proj_b[j];
  }
}

// ---------------- expand proj_w to block-diagonal f16 Mkf[96][1024] ----------------
__global__ __launch_bounds__(256) void k_expand(const float* __restrict__ proj_w,
                                                f16* __restrict__ Mkf) {
  int tid = blockIdx.x * 256 + threadIdx.x;  // 98304
  int hj = tid >> 10, d = tid & 1023;
  int h = hj / NJ, j = hj - h * NJ;
  float v = ((d >> 8) == h) ? proj_w[j * DK_ + (d & 255)] : 0.f;
  Mkf[tid] = (f16)v;
}

// ---------------- W -> f16 convert ----------------
__global__ __launch_bounds__(256) void k_wcvt(const float* __restrict__ W,
                                              f16* __restrict__ Wt) {
  int i = (blockIdx.x * 256 + threadIdx.x) * 8;
  float4 a = *(const float4*)(W + i);
  float4 b = *(const float4*)(W + i + 4);
  f16x8 o = {(f16)a.x, (f16)a.y, (f16)a.z, (f16)a.w,
             (f16)b.x, (f16)b.y, (f16)b.z, (f16)b.w};
  *(f16x8*)(Wt + i) = o;
}

// ---------------- V transpose + f16 -> blocked layout ----------------
// Vt2[bh][w 8][kt 16][ks 8][lh 2][q 32][e 8]; element = V[s][dk],
// s = kt*128+ks*16+lh*8+e, dk = w*32+q.
__global__ __launch_bounds__(256) void k_vt(const float* __restrict__ V,
                                            f16* __restrict__ Vt2) {
  __shared__ f16 tile[64][72];
  int t = threadIdx.x;
  int s0 = blockIdx.x * 64, c0 = blockIdx.y * 64;
  int bh = blockIdx.z;
  int b = bh >> 2, h = bh & 3;
  const float* src = V + (size_t)b * S_ * D_ + h * DK_ + c0;
#pragma unroll
  for (int u = 0; u < 4; ++u) {
    int row = (t >> 4) + 16 * u;
    int c4 = (t & 15) * 4;
    float4 v = *(const float4*)(src + (size_t)(s0 + row) * D_ + c4);
    tile[c4 + 0][row] = (f16)v.x;
    tile[c4 + 1][row] = (f16)v.y;
    tile[c4 + 2][row] = (f16)v.z;
    tile[c4 + 3][row] = (f16)v.w;
  }
  __syncthreads();
#pragma unroll
  for (int u = 0; u < 2; ++u) {
    int sid = t + 256 * u;
    int sgroup = sid & 7, dkl = sid >> 3;
    int dk = c0 + dkl, s = s0 + sgroup * 8;
    int wv = dk >> 5, qq = dk & 31;
    int kt = s >> 7, ks = (s >> 4) & 7, lhh = (s >> 3) & 1;
    size_t idx = ((((size_t)(bh * 8 + wv) * 16 + kt) * 8 + ks) * 2 + lhh) * 256 + qq * 8;
    *(f16x8*)(Vt2 + idx) = *(const f16x8*)&tile[dkl][sgroup * 8];
  }
}

// ---------------- unified gen via f16 MFMA + psi ----------------
__global__ __launch_bounds__(256, 1) void k_gen(
    const float* __restrict__ Q, const float* __restrict__ Kin,
    const f16* __restrict__ Mf, const f16* __restrict__ Mkf,
    const float* __restrict__ cbias, const float* __restrict__ pbias,
    f16* __restrict__ pqF, float* __restrict__ qn2,
    f16* __restrict__ pkF, float* __restrict__ kn2) {
  __shared__ __align__(16) f16 Xs[8192];
  __shared__ __align__(16) f16 Bs[24576];
  __shared__ __align__(16) float redP[4][32][96];
  __shared__ float genL[32][100];

  const int t = threadIdx.x;
  const int w = t >> 6, lane = t & 63;
  const int l31 = lane & 31, lh = lane >> 5;
  const bool isQ = blockIdx.x < 128;
  const int r0 = (isQ ? blockIdx.x : blockIdx.x - 128) * 32;
  const float* X = isQ ? Q : Kin;
  const f16* Bf = isQ ? Mf : Mkf;
  const float* bias = isQ ? cbias : pbias;

  int xrow[8], xk4[8];
#pragma unroll
  for (int u = 0; u < 8; ++u) {
    int idx = t + 256 * u;
    xrow[u] = idx >> 6;
    xk4[u] = idx & 63;
  }
  int bcol[12], bkg[12];
#pragma unroll
  for (int u = 0; u < 12; ++u) {
    int idx = t + 256 * u;
    bcol[u] = idx >> 5;
    bkg[u] = idx & 31;
  }

  float4 xr[8];
  f16x8 br[12];
#define XLOAD(K0)                                                              \
  {                                                                            \
    _Pragma("unroll") for (int u = 0; u < 8; ++u) xr[u] =                      \
        *(const float4*)(X + (size_t)(r0 + xrow[u]) * D_ + (K0) + xk4[u] * 4); \
  }
#define BLOAD(K0)                                                            \
  {                                                                          \
    _Pragma("unroll") for (int u = 0; u < 12; ++u) br[u] =                   \
        *(const f16x8*)(Bf + (size_t)bcol[u] * D_ + (K0) + bkg[u] * 8);      \
  }
#define XWRITE()                                                            \
  {                                                                         \
    _Pragma("unroll") for (int u = 0; u < 8; ++u) {                         \
      f16x4 v = {(f16)xr[u].x, (f16)xr[u].y, (f16)xr[u].z, (f16)xr[u].w};   \
      *(f16x4*)&Xs[((xk4[u] >> 1) * 32 + xrow[u]) * 8 + (xk4[u] & 1) * 4] = v; \
    }                                                                       \
  }
#define BWRITE()                                                            \
  {                                                                         \
    _Pragma("unroll") for (int u = 0; u < 12; ++u)                          \
        *(f16x8*)&Bs[(bcol[u] >> 5) * 8192 + bkg[u] * 256 +                 \
                     (bcol[u] & 31) * 8] = br[u];                           \
  }

  XLOAD(0);
  BLOAD(0);
  XWRITE();
  BWRITE();
  __syncthreads();

  f32x16 acc0{}, acc1{}, acc2{};
  for (int ch = 0; ch < 4; ++ch) {
    if (ch < 3) {
      XLOAD((ch + 1) * 256);
      BLOAD((ch + 1) * 256);
    }
#pragma unroll
    for (int i = 0; i < 4; ++i) {
      const int kk = w * 4 + i;
      const int off = (kk * 2 + lh) * 256 + l31 * 8;
      f16x8 af = *(const f16x8*)&Xs[off];
      f16x8 b0 = *(const f16x8*)&Bs[off];
      f16x8 b1 = *(const f16x8*)&Bs[8192 + off];
      f16x8 b2 = *(const f16x8*)&Bs[16384 + off];
      acc0 = __builtin_amdgcn_mfma_f32_32x32x16_f16(af, b0, acc0, 0, 0, 0);
      acc1 = __builtin_amdgcn_mfma_f32_32x32x16_f16(af, b1, acc1, 0, 0, 0);
      acc2 = __builtin_amdgcn_mfma_f32_32x32x16_f16(af, b2, acc2, 0, 0, 0);
    }
    __syncthreads();
    if (ch < 3) {
      XWRITE();
      BWRITE();
      __syncthreads();
    }
  }
#undef XLOAD
#undef BLOAD
#undef XWRITE
#undef BWRITE

#pragma unroll
  for (int r = 0; r < 16; ++r) {
    const int row = (r & 3) + 8 * (r >> 2) + 4 * lh;
    redP[w][row][l31] = acc0[r];
    redP[w][row][32 + l31] = acc1[r];
    redP[w][row][64 + l31] = acc2[r];
  }
  __syncthreads();

  {
    const int row = t >> 3, cg = t & 7;
#pragma unroll
    for (int c = 0; c < 12; ++c) {
      int col = cg * 12 + c;
      genL[row][col] = redP[0][row][col] + redP[1][row][col] +
                       redP[2][row][col] + redP[3][row][col] + bias[col];
    }
  }
  __syncthreads();

  {
    const int rg = t >> 6;
    const int hh = (t & 63) >> 4;
    const int ii = t & 15;
    const int j = ii & 7;
    f16* po = isQ ? pqF : pkF;
    float* n2o = isQ ? qn2 : kn2;
#pragma unroll 2
    for (int r = 0; r < 8; ++r) {
      int row = rg * 8 + r;
      int g = r0 + row;
      int b = g >> 11, s = g & (S_ - 1);
      const float* gl = &genL[row][hh * NJ];
      float A = gl[j], Bg = gl[8 + j];
      float Th = fminf(fmaxf(gl[16 + j], -8.f), 8.f);
      float val = (ii < 8) ? (A * expf(Th) + Bg * cosf(Th)) : (Bg * sinf(Th));
      size_t base = (size_t)(b * H_ + hh) * S_ + s;
      po[base * 16 + ii] = (f16)val;
      float sq = val * val;
#pragma unroll
      for (int off = 1; off < 16; off <<= 1) sq += __shfl_xor(sq, off);
      if (ii == 0) n2o[base] = sq;
    }
  }
}

// ---------------- MFMA flash geometric attention, split-K x2, KT=256 ----------------
// 1024 blocks: half = bid>>9, inner = bid&511. Each wave owns 32 k-entities/tile
// (2 score MFMAs); Plds 32 chunks; PV 16 MFMAs over two V subtiles (prefetched).
// Barriers: 2 per 256-k tile = 8 per block (was 16).
__global__ __launch_bounds__(512, 4) void k_attn(
    const f16* __restrict__ pqF, const float* __restrict__ qn2,
    const f16* __restrict__ pkF, const float* __restrict__ kn2,
    const f16* __restrict__ Vt2, const float* __restrict__ geo_w,
    const float* __restrict__ temp,
    float* __restrict__ pacc, float* __restrict__ pml) {
  __shared__ __align__(16) float kn2s[KT2];
  __shared__ __align__(16) float khs[KT2];
  __shared__ float mPart[8][32], sPart[8][32];
  __shared__ float mbuf[2][32];
  __shared__ __align__(16) float fL[32];
  __shared__ __align__(16) f16 Plds[32][32][8];

  const int t = threadIdx.x;
  const int w = t >> 6;
  const int lane = t & 63;
  const int q_ = lane & 31;
  const int lh = lane >> 5;

  const int bid = blockIdx.x;
  const int half = bid >> 9;
  const int inner = bid & 511;
  const int bh = inner & 7, qt = inner >> 3;
  const int q0 = qt * 32;
  const int kofs = half * (S_ / 2);

  const size_t bhS = (size_t)bh * S_;
  const f16* pkb = pkF + bhS * 16;
  const float* kn2b = kn2 + bhS + kofs;

  const float scale = 0.25f / temp[0];
  const float g0s = geo_w[0] * scale, g1s = geo_w[1] * scale, g2s = geo_w[2] * scale;
  const float g3s = geo_w[3] * scale;

  const f16x8 bq = *(const f16x8*)(pqF + (bhS + q0 + q_) * 16 + lh * 8);
  const float qn2q = qn2[bhS + q0 + q_];
  const float qh3 = sqrtf(qn2q + 1e-6f) * g3s;

  const v2f qn2v = {qn2q, qn2q};
  const v2f g0v = {g0s, g0s}, g1v = {g1s, g1s}, g2v = {g2s, g2s};
  const v2f zero2 = {0.f, 0.f}, eps2 = {1e-6f, 1e-6f};

  // wave's 32 k-entity rows: group0 at w*32, group1 at w*32+16
  const f16* ap_base = pkb + (size_t)(kofs + w * 32 + (q_ & 15)) * 16 +
                       ((q_ < 16) ? lh * 8 : (1 - lh) * 8);
  // V subtile pairs: tile index = half*8 + ktl*2 (+1)
  const f16* vt_base = Vt2 + ((size_t)(bh * 8 + w) * 16 + half * 8) * 4096 +
                       lh * 256 + q_ * 8;

  if (t < KT2) { float kv = kn2b[t]; kn2s[t] = kv; khs[t] = sqrtf(kv + 1e-6f); }
  if (t < 32) mbuf[0][t] = -INFINITY;
  float lreg = 0.f;
  f32x16 acc{};
  const f32x16 zacc{};

  // prologue prefetch
  f16x8 af0 = *(const f16x8*)ap_base;
  f16x8 af1 = *(const f16x8*)(ap_base + 256);
  f16x8 bv[8], bvB[8];
#pragma unroll
  for (int ks = 0; ks < 8; ++ks) bv[ks] = *(const f16x8*)(vt_base + ks * 512);
#pragma unroll
  for (int ks = 0; ks < 8; ++ks) bvB[ks] = *(const f16x8*)(vt_base + 4096 + ks * 512);
  __syncthreads();

  for (int ktl = 0; ktl < NTL2; ++ktl) {
    float knv = 0.f;
    if (t < KT2 && ktl + 1 < NTL2) knv = kn2b[ktl * KT2 + KT2 + t];

    // ---- scores: two 16-entity groups ----
    f16x8 a0 = af0, a1 = af1;
    if (q_ >= 16 && lh == 1) { a0 = -a0; a1 = -a1; }
    f32x16 sc0 = __builtin_amdgcn_mfma_f32_32x32x16_f16(a0, bq, zacc, 0, 0, 0);
    f32x16 sc1 = __builtin_amdgcn_mfma_f32_32x32x16_f16(a1, bq, zacc, 0, 0, 0);
    if (ktl + 1 < NTL2) {
      af0 = *(const f16x8*)(ap_base + (size_t)(ktl + 1) * KT2 * 16);
      af1 = *(const f16x8*)(ap_base + (size_t)(ktl + 1) * KT2 * 16 + 256);
    }

    v2f sv0[4], sv1[4];
    v2f tmaxv = {-INFINITY, -INFINITY};
#pragma unroll
    for (int rp = 0; rp < 4; ++rp) {
      const int r = 2 * rp;
      const int kb2 = w * 32 + 4 * lh + (rp & 1) * 2 + (rp >> 1) * 8;
      v2f tn = {sc0[r], sc0[r + 1]};
      v2f sp = {sc0[r + 8], sc0[r + 9]};
      v2f kn2p = *(const v2f*)&kn2s[kb2];
      v2f khp = *(const v2f*)&khs[kb2];
      v2f wr = qn2v * kn2p - tn * tn - sp * sp;
      wr = __builtin_elementwise_max(wr, zero2) + eps2;
      v2f wg = {sqrtf(wr.x), sqrtf(wr.y)};
      v2f s2 = g0v * wg + g1v * tn + g2v * sp + qh3 * khp;
      sv0[rp] = s2;
      tmaxv = __builtin_elementwise_max(tmaxv, s2);
    }
#pragma unroll
    for (int rp = 0; rp < 4; ++rp) {
      const int r = 2 * rp;
      const int kb2 = w * 32 + 16 + 4 * lh + (rp & 1) * 2 + (rp >> 1) * 8;
      v2f tn = {sc1[r], sc1[r + 1]};
      v2f sp = {sc1[r + 8], sc1[r + 9]};
      v2f kn2p = *(const v2f*)&kn2s[kb2];
      v2f khp = *(const v2f*)&khs[kb2];
      v2f wr = qn2v * kn2p - tn * tn - sp * sp;
      wr = __builtin_elementwise_max(wr, zero2) + eps2;
      v2f wg = {sqrtf(wr.x), sqrtf(wr.y)};
      v2f s2 = g0v * wg + g1v * tn + g2v * sp + qh3 * khp;
      sv1[rp] = s2;
      tmaxv = __builtin_elementwise_max(tmaxv, s2);
    }
    float tmax = fmaxf(tmaxv.x, tmaxv.y);
    tmax = fmaxf(tmax, __shfl_xor(tmax, 32));
    if (lh == 0) mPart[w][q_] = tmax;
    __syncthreads();  // bar1

    float mold = mbuf[ktl & 1][q_];
    float mn = mold;
#pragma unroll
    for (int i = 0; i < 8; ++i) mn = fmaxf(mn, mPart[i][q_]);
    if (t < KT2 && ktl + 1 < NTL2) {
      kn2s[t] = knv;
      khs[t] = sqrtf(knv + 1e-6f);
    }
    const v2f mnv = {mn, mn};
    float pv0[8], pv1[8];
    v2f psv = {0.f, 0.f};
#pragma unroll
    for (int rp = 0; rp < 4; ++rp) {
      v2f d = sv0[rp] - mnv;
      v2f p2 = {__expf(d.x), __expf(d.y)};
      pv0[2 * rp] = p2.x;
      pv0[2 * rp + 1] = p2.y;
      psv += p2;
    }
#pragma unroll
    for (int rp = 0; rp < 4; ++rp) {
      v2f d = sv1[rp] - mnv;
      v2f p2 = {__expf(d.x), __expf(d.y)};
      pv1[2 * rp] = p2.x;
      pv1[2 * rp + 1] = p2.y;
      psv += p2;
    }
    float ps = psv.x + psv.y;
    ps += __shfl_xor(ps, 32);
    if (lh == 0) sPart[w][q_] = ps;
    if (w == 0 && lh == 0) {
      mbuf[(ktl & 1) ^ 1][q_] = mn;
      fL[q_] = __expf(mold - mn);
    }
    {
      f16x2 a01 = {(f16)pv0[0], (f16)pv0[1]};
      f16x2 a23 = {(f16)pv0[2], (f16)pv0[3]};
      f16x2 a45 = {(f16)pv0[4], (f16)pv0[5]};
      f16x2 a67 = {(f16)pv0[6], (f16)pv0[7]};
      *(f16x2*)&Plds[4 * w + 0][q_][4 * lh + 0] = a01;
      *(f16x2*)&Plds[4 * w + 0][q_][4 * lh + 2] = a23;
      *(f16x2*)&Plds[4 * w + 1][q_][4 * lh + 0] = a45;
      *(f16x2*)&Plds[4 * w + 1][q_][4 * lh + 2] = a67;
      f16x2 b01 = {(f16)pv1[0], (f16)pv1[1]};
      f16x2 b23 = {(f16)pv1[2], (f16)pv1[3]};
      f16x2 b45 = {(f16)pv1[4], (f16)pv1[5]};
      f16x2 b67 = {(f16)pv1[6], (f16)pv1[7]};
      *(f16x2*)&Plds[4 * w + 2][q_][4 * lh + 0] = b01;
      *(f16x2*)&Plds[4 * w + 2][q_][4 * lh + 2] = b23;
      *(f16x2*)&Plds[4 * w + 3][q_][4 * lh + 0] = b45;
      *(f16x2*)&Plds[4 * w + 3][q_][4 * lh + 2] = b67;
    }
    __syncthreads();  // bar2

    // ---- PV (16 MFMAs over 2 V subtiles) ----
    {
      float4 f0 = *(const float4*)&fL[0 + 4 * lh];
      float4 f1 = *(const float4*)&fL[8 + 4 * lh];
      float4 f2 = *(const float4*)&fL[16 + 4 * lh];
      float4 f3 = *(const float4*)&fL[24 + 4 * lh];
      acc[0] *= f0.x; acc[1] *= f0.y; acc[2] *= f0.z; acc[3] *= f0.w;
      acc[4] *= f1.x; acc[5] *= f1.y; acc[6] *= f1.z; acc[7] *= f1.w;
      acc[8] *= f2.x; acc[9] *= f2.y; acc[10] *= f2.z; acc[11] *= f2.w;
      acc[12] *= f3.x; acc[13] *= f3.y; acc[14] *= f3.z; acc[15] *= f3.w;
    }
    if (w == 0 && lh == 0) {
      float s8 = 0.f;
#pragma unroll
      for (int i = 0; i < 8; ++i) s8 += sPart[i][q_];
      lreg = lreg * fL[q_] + s8;
    }
#pragma unroll
    for (int ks = 0; ks < 8; ++ks) {
      f16x8 pa = *(const f16x8*)&Plds[2 * ks + lh][q_][0];
      acc = __builtin_amdgcn_mfma_f32_32x32x16_f16(pa, bv[ks], acc, 0, 0, 0);
    }
#pragma unroll
    for (int ks = 8; ks < 16; ++ks) {
      f16x8 pa = *(const f16x8*)&Plds[2 * ks + lh][q_][0];
      acc = __builtin_amdgcn_mfma_f32_32x32x16_f16(pa, bvB[ks - 8], acc, 0, 0, 0);
    }
    if (ktl + 1 < NTL2) {
      const f16* vbn = vt_base + (size_t)(ktl + 1) * 8192;
#pragma unroll
      for (int ks = 0; ks < 8; ++ks) bv[ks] = *(const f16x8*)(vbn + ks * 512);
#pragma unroll
      for (int ks = 0; ks < 8; ++ks) bvB[ks] = *(const f16x8*)(vbn + 4096 + ks * 512);
    }
  }

  // ---- write partials (NTL2 even -> final m in mbuf[0]) ----
  if (w == 0 && lh == 0) {
    pml[(size_t)bid * 64 + q_] = mbuf[0][q_];
    pml[(size_t)bid * 64 + 32 + q_] = lreg;
  }
#pragma unroll
  for (int r = 0; r < 16; ++r) {
    const int row = (r & 3) + 8 * (r >> 2) + 4 * lh;
    pacc[((size_t)bid * 32 + row) * 256 + w * 32 + q_] = acc[r];
  }
}

// ---------------- split-K merge: combine 2 partials -> f16 attn ----------------
__global__ __launch_bounds__(256) void k_merge(const float* __restrict__ pacc,
                                               const float* __restrict__ pml,
                                               f16* __restrict__ attnF) {
  const int inner = blockIdx.x;
  const int bh = inner & 7, qt = inner >> 3;
  const int b = bh >> 2, h = bh & 3;
  const int t = threadIdx.x;
  const int q = t >> 3, dgrp = t & 7;
  const float* a0 = pacc + ((size_t)inner * 32 + q) * 256 + dgrp * 32;
  const float* a1 = pacc + ((size_t)(inner + 512) * 32 + q) * 256 + dgrp * 32;
  const float m0 = pml[(size_t)inner * 64 + q];
  const float l0 = pml[(size_t)inner * 64 + 32 + q];
  const float m1 = pml[(size_t)(inner + 512) * 64 + q];
  const float l1 = pml[(size_t)(inner + 512) * 64 + 32 + q];
  const float m = fmaxf(m0, m1);
  const float e0 = __expf(m0 - m), e1 = __expf(m1 - m);
  const float linv = 1.f / (l0 * e0 + l1 * e1);
  const float c0 = e0 * linv, c1 = e1 * linv;
  f16* dst = attnF + ((size_t)b * S_ + qt * 32 + q) * D_ + h * DK_ + dgrp * 32;
#pragma unroll
  for (int i = 0; i < 4; ++i) {
    float4 x0 = ((const float4*)a0)[2 * i];
    float4 y0 = ((const float4*)a0)[2 * i + 1];
    float4 x1 = ((const float4*)a1)[2 * i];
    float4 y1 = ((const float4*)a1)[2 * i + 1];
    f16x8 o = {(f16)(x0.x * c0 + x1.x * c1), (f16)(x0.y * c0 + x1.y * c1),
               (f16)(x0.z * c0 + x1.z * c1), (f16)(x0.w * c0 + x1.w * c1),
               (f16)(y0.x * c0 + y1.x * c1), (f16)(y0.y * c0 + y1.y * c1),
               (f16)(y0.z * c0 + y1.z * c1), (f16)(y0.w * c0 + y1.w * c1)};
    *(f16x8*)(dst + 8 * i) = o;
  }
}

// ---------------- output projection: LDS-staged f16 MFMA GEMM ----------------
__global__ __launch_bounds__(256, 1) void k_wo(const f16* __restrict__ A,
                                               const f16* __restrict__ Wt,
                                               const float* __restrict__ bias,
                                               float* __restrict__ C) {
  __shared__ __align__(16) f16 Abuf[2][128 * 64];
  __shared__ __align__(16) f16 Bbuf[2][128 * 64];
  const int t = threadIdx.x;
  const int w = t >> 6, lane = t & 63;
  const int wr = w >> 1, wc = w & 1;
  const int brow = blockIdx.y * 128, bcol = blockIdx.x * 128;

  int srow[4], skof[4];
#pragma unroll
  for (int u = 0; u < 4; ++u) {
    int c = t + 256 * u;
    int sub = c >> 6, l6 = c & 63;
    srow[u] = (sub >> 2) * 32 + (l6 & 31);
    skof[u] = (sub & 3) * 16 + (l6 >> 5) * 8;
  }

  uint4 ra0, ra1, ra2, ra3, rb0, rb1, rb2, rb3;
#define LOAD_TILE(K0)                                                        \
  {                                                                          \
    ra0 = *(const uint4*)(A + (size_t)(brow + srow[0]) * D_ + (K0) + skof[0]); \
    ra1 = *(const uint4*)(A + (size_t)(brow + srow[1]) * D_ + (K0) + skof[1]); \
    ra2 = *(const uint4*)(A + (size_t)(brow + srow[2]) * D_ + (K0) + skof[2]); \
    ra3 = *(const uint4*)(A + (size_t)(brow + srow[3]) * D_ + (K0) + skof[3]); \
    rb0 = *(const uint4*)(Wt + (size_t)(bcol + srow[0]) * D_ + (K0) + skof[0]); \
    rb1 = *(const uint4*)(Wt + (size_t)(bcol + srow[1]) * D_ + (K0) + skof[1]); \
    rb2 = *(const uint4*)(Wt + (size_t)(bcol + srow[2]) * D_ + (K0) + skof[2]); \
    rb3 = *(const uint4*)(Wt + (size_t)(bcol + srow[3]) * D_ + (K0) + skof[3]); \
  }
#define WRITE_TILE(BUF)                                       \
  {                                                           \
    *(uint4*)&Abuf[BUF][(t + 0) * 8] = ra0;                   \
    *(uint4*)&Abuf[BUF][(t + 256) * 8] = ra1;                 \
    *(uint4*)&Abuf[BUF][(t + 512) * 8] = ra2;                 \
    *(uint4*)&Abuf[BUF][(t + 768) * 8] = ra3;                 \
    *(uint4*)&Bbuf[BUF][(t + 0) * 8] = rb0;                   \
    *(uint4*)&Bbuf[BUF][(t + 256) * 8] = rb1;                 \
    *(uint4*)&Bbuf[BUF][(t + 512) * 8] = rb2;                 \
    *(uint4*)&Bbuf[BUF][(t + 768) * 8] = rb3;                 \
  }

  f32x16 acc00{}, acc01{}, acc10{}, acc11{};

  LOAD_TILE(0);
  WRITE_TILE(0);
  LOAD_TILE(64);
  __syncthreads();

  int cur = 0;
  for (int kt = 0; kt < 16; ++kt) {
    const int am0 = (wr * 2 + 0) * 4, am1 = (wr * 2 + 1) * 4;
    const int bn0 = (wc * 2 + 0) * 4, bn1 = (wc * 2 + 1) * 4;
#pragma unroll
    for (int kk = 0; kk < 4; ++kk) {
      f16x8 a0 = *(const f16x8*)&Abuf[cur][(am0 + kk) * 512 + lane * 8];
      f16x8 a1 = *(const f16x8*)&Abuf[cur][(am1 + kk) * 512 + lane * 8];
      f16x8 b0 = *(const f16x8*)&Bbuf[cur][(bn0 + kk) * 512 + lane * 8];
      f16x8 b1 = *(const f16x8*)&Bbuf[cur][(bn1 + kk) * 512 + lane * 8];
      acc00 = __builtin_amdgcn_mfma_f32_32x32x16_f16(a0, b0, acc00, 0, 0, 0);
      acc01 = __builtin_amdgcn_mfma_f32_32x32x16_f16(a0, b1, acc01, 0, 0, 0);
      acc10 = __builtin_amdgcn_mfma_f32_32x32x16_f16(a1, b0, acc10, 0, 0, 0);
      acc11 = __builtin_amdgcn_mfma_f32_32x32x16_f16(a1, b1, acc11, 0, 0, 0);
    }
    if (kt + 1 < 16) {
      WRITE_TILE(cur ^ 1);
      if (kt + 2 < 16) LOAD_TILE((kt + 2) * 64);
    }
    __syncthreads();
    cur ^= 1;
  }

  const int l31 = lane & 31, lh = lane >> 5;
  const float bv0 = bias[bcol + (wc * 2 + 0) * 32 + l31];
  const float bv1 = bias[bcol + (wc * 2 + 1) * 32 + l31];
#pragma unroll
  for (int r = 0; r < 16; ++r) {
    const int row = (r & 3) + 8 * (r >> 2) + 4 * lh;
    const size_t m0r = (size_t)(brow + (wr * 2 + 0) * 32 + row) * D_;
    const size_t m1r = (size_t)(brow + (wr * 2 + 1) * 32 + row) * D_;
    C[m0r + bcol + (wc * 2 + 0) * 32 + l31] = acc00[r] + bv0;
    C[m0r + bcol + (wc * 2 + 1) * 32 + l31] = acc01[r] + bv1;
    C[m1r + bcol + (wc * 2 + 0) * 32 + l31] = acc10[r] + bv0;
    C[m1r + bcol + (wc * 2 + 1) * 32 + l31] = acc11[r] + bv1;
  }
#undef LOAD_TILE
#undef WRITE_TILE
}

extern "C" void kernel_launch(void* const* d_in, const int* in_sizes, int n_in,
                              void* d_out, int out_size, void* d_ws, size_t ws_size,
                              hipStream_t stream) {
  const float* Q_input = (const float*)d_in[0];
  const float* K = (const float*)d_in[1];
  const float* V = (const float*)d_in[2];
  const float* Wq_w = (const float*)d_in[4];
  const float* Wq_b = (const float*)d_in[5];
  const float* Wo_w = (const float*)d_in[6];
  const float* Wo_b = (const float*)d_in[7];
  const float* proj_w = (const float*)d_in[8];
  const float* proj_b = (const float*)d_in[9];
  const float* geo_w = (const float*)d_in[10];
  const float* temp = (const float*)d_in[11];

  float* ws = (float*)d_ws;
  float* cbias = ws;                       // 128
  float* pbias = cbias + 128;              // 128
  f16* Mf = (f16*)(pbias + 128);           // 98304 f16
  f16* Mkf = Mf + 98304;                   // 98304 f16
  float* qn2 = (float*)(Mkf + 98304);      // 16384
  float* kn2 = qn2 + 16384;                // 16384
  f16* pqF = (f16*)(kn2 + 16384);          // 262144 f16
  f16* pkF = pqF + 262144;                 // 262144 f16
  f16* Vt2 = pkF + 262144;                 // 2097152 f16
  f16* attnF = Vt2 + 2097152;              // 4194304 f16 (B*S*D)
  f16* Wf = attnF + 4194304;               // 1048576 f16
  float* pacc = (float*)(Wf + 1048576);    // 8388608 f32
  float* pml = pacc + 8388608;             // 65536 f32
  float* out = (float*)d_out;

  k_fuse<<<dim3(384), dim3(256), 0, stream>>>(Wq_w, proj_w, Mf);
  k_fuse_bias<<<dim3(1), dim3(128), 0, stream>>>(Wq_b, proj_w, proj_b, cbias, pbias);
  k_expand<<<dim3(384), dim3(256), 0, stream>>>(proj_w, Mkf);
  k_wcvt<<<dim3(512), dim3(256), 0, stream>>>(Wo_w, Wf);
  k_vt<<<dim3(32, 4, 8), dim3(256), 0, stream>>>(V, Vt2);
  k_gen<<<dim3(256), dim3(256), 0, stream>>>(Q_input, K, Mf, Mkf, cbias, pbias,
                                             pqF, qn2, pkF, kn2);
  k_attn<<<dim3(1024), dim3(512), 0, stream>>>(pqF, qn2, pkF, kn2, Vt2, geo_w,
                                               temp, pacc, pml);
  k_merge<<<dim3(512), dim3(256), 0, stream>>>(pacc, pml, attnF);
  k_wo<<<dim3(8, 32), dim3(256), 0, stream>>>(attnF, Wf, Wo_b, out);
}

// Round 16
// 142.005 us; speedup vs baseline: 1.4760x; 1.4760x over previous
//
#include <hip/hip_runtime.h>
#include <hip/hip_bf16.h>
#include <math.h>

#define B_ 2
#define S_ 2048
#define D_ 1024
#define H_ 4
#define DK_ 256
#define NJ 24
#define NG 96
#define KTA 128
#define NT2 (S_ / KTA)
#define NTL (NT2 / 2)

typedef _Float16 f16;
typedef _Float16 f16x2 __attribute__((ext_vector_type(2)));
typedef _Float16 f16x4 __attribute__((ext_vector_type(4)));
typedef _Float16 f16x8 __attribute__((ext_vector_type(8)));
typedef float f32x16 __attribute__((ext_vector_type(16)));
typedef float v2f __attribute__((ext_vector_type(2)));

// ---------------- fold Wq into proj -> f16 Mf[hj][d] ----------------
__global__ __launch_bounds__(256) void k_fuse(const float* __restrict__ Wq_w,
                                              const float* __restrict__ proj_w,
                                              f16* __restrict__ Mf) {
  int tid = blockIdx.x * 256 + threadIdx.x;
  int hj = tid >> 10;
  int d = tid & 1023;
  int h = hj / NJ, j = hj - h * NJ;
  const float* wq = Wq_w + (size_t)(h * DK_) * D_ + d;
  const float* pw = proj_w + j * DK_;
  float acc = 0.f;
#pragma unroll 8
  for (int k = 0; k < DK_; ++k) acc += wq[(size_t)k * D_] * pw[k];
  Mf[(size_t)hj * D_ + d] = (f16)acc;
}

__global__ void k_fuse_bias(const float* __restrict__ Wq_b,
                            const float* __restrict__ proj_w,
                            const float* __restrict__ proj_b,
                            float* __restrict__ cbias,
                            float* __restrict__ pbias) {
  int hj = threadIdx.x;
  if (hj < NG) {
    int h = hj / NJ, j = hj - h * NJ;
    float acc = proj_b[j];
    for (int k = 0; k < DK_; ++k) acc += Wq_b[h * DK_ + k] * proj_w[j * DK_ + k];
    cbias[hj] = acc;
    pbias[hj] = proj_b[j];
  }
}

// ---------------- expand proj_w to block-diagonal f16 Mkf[96][1024] ----------------
__global__ __launch_bounds__(256) void k_expand(const float* __restrict__ proj_w,
                                                f16* __restrict__ Mkf) {
  int tid = blockIdx.x * 256 + threadIdx.x;  // 98304
  int hj = tid >> 10, d = tid & 1023;
  int h = hj / NJ, j = hj - h * NJ;
  float v = ((d >> 8) == h) ? proj_w[j * DK_ + (d & 255)] : 0.f;
  Mkf[tid] = (f16)v;
}

// ---------------- W -> f16 convert ----------------
__global__ __launch_bounds__(256) void k_wcvt(const float* __restrict__ W,
                                              f16* __restrict__ Wt) {
  int i = (blockIdx.x * 256 + threadIdx.x) * 8;
  float4 a = *(const float4*)(W + i);
  float4 b = *(const float4*)(W + i + 4);
  f16x8 o = {(f16)a.x, (f16)a.y, (f16)a.z, (f16)a.w,
             (f16)b.x, (f16)b.y, (f16)b.z, (f16)b.w};
  *(f16x8*)(Wt + i) = o;
}

// ---------------- V transpose + f16 -> blocked layout ----------------
__global__ __launch_bounds__(256) void k_vt(const float* __restrict__ V,
                                            f16* __restrict__ Vt2) {
  __shared__ f16 tile[64][72];
  int t = threadIdx.x;
  int s0 = blockIdx.x * 64, c0 = blockIdx.y * 64;
  int bh = blockIdx.z;
  int b = bh >> 2, h = bh & 3;
  const float* src = V + (size_t)b * S_ * D_ + h * DK_ + c0;
#pragma unroll
  for (int u = 0; u < 4; ++u) {
    int row = (t >> 4) + 16 * u;
    int c4 = (t & 15) * 4;
    float4 v = *(const float4*)(src + (size_t)(s0 + row) * D_ + c4);
    tile[c4 + 0][row] = (f16)v.x;
    tile[c4 + 1][row] = (f16)v.y;
    tile[c4 + 2][row] = (f16)v.z;
    tile[c4 + 3][row] = (f16)v.w;
  }
  __syncthreads();
#pragma unroll
  for (int u = 0; u < 2; ++u) {
    int sid = t + 256 * u;
    int sgroup = sid & 7, dkl = sid >> 3;
    int dk = c0 + dkl, s = s0 + sgroup * 8;
    int wv = dk >> 5, qq = dk & 31;
    int kt = s >> 7, ks = (s >> 4) & 7, lhh = (s >> 3) & 1;
    size_t idx = ((((size_t)(bh * 8 + wv) * 16 + kt) * 8 + ks) * 2 + lhh) * 256 + qq * 8;
    *(f16x8*)(Vt2 + idx) = *(const f16x8*)&tile[dkl][sgroup * 8];
  }
}

// ---------------- unified gen via f16 MFMA + psi ----------------
__global__ __launch_bounds__(256, 1) void k_gen(
    const float* __restrict__ Q, const float* __restrict__ Kin,
    const f16* __restrict__ Mf, const f16* __restrict__ Mkf,
    const float* __restrict__ cbias, const float* __restrict__ pbias,
    f16* __restrict__ pqF, float* __restrict__ qn2,
    f16* __restrict__ pkF, float* __restrict__ kn2) {
  __shared__ __align__(16) f16 Xs[8192];
  __shared__ __align__(16) f16 Bs[24576];
  __shared__ __align__(16) float redP[4][32][96];
  __shared__ float genL[32][100];

  const int t = threadIdx.x;
  const int w = t >> 6, lane = t & 63;
  const int l31 = lane & 31, lh = lane >> 5;
  const bool isQ = blockIdx.x < 128;
  const int r0 = (isQ ? blockIdx.x : blockIdx.x - 128) * 32;
  const float* X = isQ ? Q : Kin;
  const f16* Bf = isQ ? Mf : Mkf;
  const float* bias = isQ ? cbias : pbias;

  int xrow[8], xk4[8];
#pragma unroll
  for (int u = 0; u < 8; ++u) {
    int idx = t + 256 * u;
    xrow[u] = idx >> 6;
    xk4[u] = idx & 63;
  }
  int bcol[12], bkg[12];
#pragma unroll
  for (int u = 0; u < 12; ++u) {
    int idx = t + 256 * u;
    bcol[u] = idx >> 5;
    bkg[u] = idx & 31;
  }

  float4 xr[8];
  f16x8 br[12];
#define XLOAD(K0)                                                              \
  {                                                                            \
    _Pragma("unroll") for (int u = 0; u < 8; ++u) xr[u] =                      \
        *(const float4*)(X + (size_t)(r0 + xrow[u]) * D_ + (K0) + xk4[u] * 4); \
  }
#define BLOAD(K0)                                                            \
  {                                                                          \
    _Pragma("unroll") for (int u = 0; u < 12; ++u) br[u] =                   \
        *(const f16x8*)(Bf + (size_t)bcol[u] * D_ + (K0) + bkg[u] * 8);      \
  }
#define XWRITE()                                                            \
  {                                                                         \
    _Pragma("unroll") for (int u = 0; u < 8; ++u) {                         \
      f16x4 v = {(f16)xr[u].x, (f16)xr[u].y, (f16)xr[u].z, (f16)xr[u].w};   \
      *(f16x4*)&Xs[((xk4[u] >> 1) * 32 + xrow[u]) * 8 + (xk4[u] & 1) * 4] = v; \
    }                                                                       \
  }
#define BWRITE()                                                            \
  {                                                                         \
    _Pragma("unroll") for (int u = 0; u < 12; ++u)                          \
        *(f16x8*)&Bs[(bcol[u] >> 5) * 8192 + bkg[u] * 256 +                 \
                     (bcol[u] & 31) * 8] = br[u];                           \
  }

  XLOAD(0);
  BLOAD(0);
  XWRITE();
  BWRITE();
  __syncthreads();

  f32x16 acc0{}, acc1{}, acc2{};
  for (int ch = 0; ch < 4; ++ch) {
    if (ch < 3) {
      XLOAD((ch + 1) * 256);
      BLOAD((ch + 1) * 256);
    }
#pragma unroll
    for (int i = 0; i < 4; ++i) {
      const int kk = w * 4 + i;
      const int off = (kk * 2 + lh) * 256 + l31 * 8;
      f16x8 af = *(const f16x8*)&Xs[off];
      f16x8 b0 = *(const f16x8*)&Bs[off];
      f16x8 b1 = *(const f16x8*)&Bs[8192 + off];
      f16x8 b2 = *(const f16x8*)&Bs[16384 + off];
      acc0 = __builtin_amdgcn_mfma_f32_32x32x16_f16(af, b0, acc0, 0, 0, 0);
      acc1 = __builtin_amdgcn_mfma_f32_32x32x16_f16(af, b1, acc1, 0, 0, 0);
      acc2 = __builtin_amdgcn_mfma_f32_32x32x16_f16(af, b2, acc2, 0, 0, 0);
    }
    __syncthreads();
    if (ch < 3) {
      XWRITE();
      BWRITE();
      __syncthreads();
    }
  }
#undef XLOAD
#undef BLOAD
#undef XWRITE
#undef BWRITE

#pragma unroll
  for (int r = 0; r < 16; ++r) {
    const int row = (r & 3) + 8 * (r >> 2) + 4 * lh;
    redP[w][row][l31] = acc0[r];
    redP[w][row][32 + l31] = acc1[r];
    redP[w][row][64 + l31] = acc2[r];
  }
  __syncthreads();

  {
    const int row = t >> 3, cg = t & 7;
#pragma unroll
    for (int c = 0; c < 12; ++c) {
      int col = cg * 12 + c;
      genL[row][col] = redP[0][row][col] + redP[1][row][col] +
                       redP[2][row][col] + redP[3][row][col] + bias[col];
    }
  }
  __syncthreads();

  {
    const int rg = t >> 6;
    const int hh = (t & 63) >> 4;
    const int ii = t & 15;
    const int j = ii & 7;
    f16* po = isQ ? pqF : pkF;
    float* n2o = isQ ? qn2 : kn2;
#pragma unroll 2
    for (int r = 0; r < 8; ++r) {
      int row = rg * 8 + r;
      int g = r0 + row;
      int b = g >> 11, s = g & (S_ - 1);
      const float* gl = &genL[row][hh * NJ];
      float A = gl[j], Bg = gl[8 + j];
      float Th = fminf(fmaxf(gl[16 + j], -8.f), 8.f);
      float val = (ii < 8) ? (A * expf(Th) + Bg * cosf(Th)) : (Bg * sinf(Th));
      size_t base = (size_t)(b * H_ + hh) * S_ + s;
      po[base * 16 + ii] = (f16)val;
      float sq = val * val;
#pragma unroll
      for (int off = 1; off < 16; off <<= 1) sq += __shfl_xor(sq, off);
      if (ii == 0) n2o[base] = sq;
    }
  }
}

// ---------------- MFMA flash geometric attention, split-K x2 (R13 structure) ----------------
// + T5 s_setprio around MFMA clusters (zero register cost).
__global__ __launch_bounds__(512, 4) void k_attn(
    const f16* __restrict__ pqF, const float* __restrict__ qn2,
    const f16* __restrict__ pkF, const float* __restrict__ kn2,
    const f16* __restrict__ Vt2, const float* __restrict__ geo_w,
    const float* __restrict__ temp,
    float* __restrict__ pacc, float* __restrict__ pml) {
  __shared__ __align__(16) float kn2s[KTA];
  __shared__ __align__(16) float khs[KTA];
  __shared__ float mPart[8][32], sPart[8][32];
  __shared__ float mbuf[2][32];
  __shared__ __align__(16) float fL[32];
  __shared__ __align__(16) f16 Plds[16][32][8];

  const int t = threadIdx.x;
  const int w = t >> 6;
  const int lane = t & 63;
  const int q_ = lane & 31;
  const int lh = lane >> 5;

  const int bid = blockIdx.x;
  const int half = bid >> 9;
  const int inner = bid & 511;
  const int bh = inner & 7, qt = inner >> 3;
  const int q0 = qt * 32;
  const int kofs = half * (S_ / 2);

  const size_t bhS = (size_t)bh * S_;
  const f16* pkb = pkF + bhS * 16;
  const float* kn2b = kn2 + bhS + kofs;

  const float scale = 0.25f / temp[0];
  const float g0s = geo_w[0] * scale, g1s = geo_w[1] * scale, g2s = geo_w[2] * scale;
  const float g3s = geo_w[3] * scale;

  const f16x8 bq = *(const f16x8*)(pqF + (bhS + q0 + q_) * 16 + lh * 8);
  const float qn2q = qn2[bhS + q0 + q_];
  const float qh3 = sqrtf(qn2q + 1e-6f) * g3s;

  const v2f qn2v = {qn2q, qn2q};
  const v2f g0v = {g0s, g0s}, g1v = {g1s, g1s}, g2v = {g2s, g2s};
  const v2f zero2 = {0.f, 0.f}, eps2 = {1e-6f, 1e-6f};

  const f16* ap_base = pkb + (size_t)(kofs + w * 16 + (q_ & 15)) * 16 +
                       ((q_ < 16) ? lh * 8 : (1 - lh) * 8);
  const f16* vb_lane = Vt2 + ((size_t)(bh * 8 + w) * 16 + half * NTL) * 4096 +
                       lh * 256 + q_ * 8;

  if (t < KTA) { float kv = kn2b[t]; kn2s[t] = kv; khs[t] = sqrtf(kv + 1e-6f); }
  if (t < 32) mbuf[0][t] = -INFINITY;
  float lreg = 0.f;
  f32x16 acc{};
  const f32x16 zacc{};

  f16x8 af = *(const f16x8*)ap_base;
  f16x8 bv[8];
#pragma unroll
  for (int ks = 0; ks < 8; ++ks) bv[ks] = *(const f16x8*)(vb_lane + ks * 512);
  __syncthreads();

  for (int ktl = 0; ktl < NTL; ++ktl) {
    const int k0l = ktl * KTA;

    float knv = 0.f;
    if (t < KTA && ktl + 1 < NTL) knv = kn2b[k0l + KTA + t];

    f16x8 afx = af;
    if (q_ >= 16 && lh == 1) afx = -afx;
    __builtin_amdgcn_s_setprio(1);
    f32x16 sc = __builtin_amdgcn_mfma_f32_32x32x16_f16(afx, bq, zacc, 0, 0, 0);
    __builtin_amdgcn_s_setprio(0);
    if (ktl + 1 < NTL) af = *(const f16x8*)(ap_base + (size_t)(k0l + KTA) * 16);

    v2f svv[4];
    v2f tmaxv = {-INFINITY, -INFINITY};
#pragma unroll
    for (int rp = 0; rp < 4; ++rp) {
      const int r = 2 * rp;
      const int kb2 = w * 16 + 4 * lh + (rp & 1) * 2 + (rp >> 1) * 8;
      v2f tn = {sc[r], sc[r + 1]};
      v2f sp = {sc[r + 8], sc[r + 9]};
      v2f kn2p = *(const v2f*)&kn2s[kb2];
      v2f khp = *(const v2f*)&khs[kb2];
      v2f wr = qn2v * kn2p - tn * tn - sp * sp;
      wr = __builtin_elementwise_max(wr, zero2) + eps2;
      v2f wg = {sqrtf(wr.x), sqrtf(wr.y)};
      v2f sv2 = g0v * wg + g1v * tn + g2v * sp + qh3 * khp;
      svv[rp] = sv2;
      tmaxv = __builtin_elementwise_max(tmaxv, sv2);
    }
    float tmax = fmaxf(tmaxv.x, tmaxv.y);
    tmax = fmaxf(tmax, __shfl_xor(tmax, 32));
    if (lh == 0) mPart[w][q_] = tmax;
    __syncthreads();  // bar1

    float mold = mbuf[ktl & 1][q_];
    float mn = mold;
#pragma unroll
    for (int i = 0; i < 8; ++i) mn = fmaxf(mn, mPart[i][q_]);
    if (t < KTA && ktl + 1 < NTL) {
      kn2s[t] = knv;
      khs[t] = sqrtf(knv + 1e-6f);
    }
    const v2f mnv = {mn, mn};
    float pv[8];
    v2f psv = {0.f, 0.f};
#pragma unroll
    for (int rp = 0; rp < 4; ++rp) {
      v2f d = svv[rp] - mnv;
      v2f p2 = {__expf(d.x), __expf(d.y)};
      pv[2 * rp] = p2.x;
      pv[2 * rp + 1] = p2.y;
      psv += p2;
    }
    float ps = psv.x + psv.y;
    ps += __shfl_xor(ps, 32);
    if (lh == 0) sPart[w][q_] = ps;
    if (w == 0 && lh == 0) {
      mbuf[(ktl & 1) ^ 1][q_] = mn;
      fL[q_] = __expf(mold - mn);
    }
    {
      f16x2 p01 = {(f16)pv[0], (f16)pv[1]};
      f16x2 p23 = {(f16)pv[2], (f16)pv[3]};
      f16x2 p45 = {(f16)pv[4], (f16)pv[5]};
      f16x2 p67 = {(f16)pv[6], (f16)pv[7]};
      *(f16x2*)&Plds[2 * w + 0][q_][4 * lh + 0] = p01;
      *(f16x2*)&Plds[2 * w + 0][q_][4 * lh + 2] = p23;
      *(f16x2*)&Plds[2 * w + 1][q_][4 * lh + 0] = p45;
      *(f16x2*)&Plds[2 * w + 1][q_][4 * lh + 2] = p67;
    }
    __syncthreads();  // bar2

    // ---- PV ----
    {
      float4 f0 = *(const float4*)&fL[0 + 4 * lh];
      float4 f1 = *(const float4*)&fL[8 + 4 * lh];
      float4 f2 = *(const float4*)&fL[16 + 4 * lh];
      float4 f3 = *(const float4*)&fL[24 + 4 * lh];
      acc[0] *= f0.x; acc[1] *= f0.y; acc[2] *= f0.z; acc[3] *= f0.w;
      acc[4] *= f1.x; acc[5] *= f1.y; acc[6] *= f1.z; acc[7] *= f1.w;
      acc[8] *= f2.x; acc[9] *= f2.y; acc[10] *= f2.z; acc[11] *= f2.w;
      acc[12] *= f3.x; acc[13] *= f3.y; acc[14] *= f3.z; acc[15] *= f3.w;
    }
    if (w == 0 && lh == 0) {
      float s8 = 0.f;
#pragma unroll
      for (int i = 0; i < 8; ++i) s8 += sPart[i][q_];
      lreg = lreg * fL[q_] + s8;
    }
    __builtin_amdgcn_s_setprio(1);
#pragma unroll
    for (int ks = 0; ks < 8; ++ks) {
      f16x8 pa = *(const f16x8*)&Plds[2 * ks + lh][q_][0];
      acc = __builtin_amdgcn_mfma_f32_32x32x16_f16(pa, bv[ks], acc, 0, 0, 0);
    }
    __builtin_amdgcn_s_setprio(0);
    if (ktl + 1 < NTL) {
      const f16* vbn = vb_lane + (size_t)(ktl + 1) * 4096;
#pragma unroll
      for (int ks = 0; ks < 8; ++ks) bv[ks] = *(const f16x8*)(vbn + ks * 512);
    }
  }

  if (w == 0 && lh == 0) {
    pml[(size_t)bid * 64 + q_] = mbuf[0][q_];
    pml[(size_t)bid * 64 + 32 + q_] = lreg;
  }
#pragma unroll
  for (int r = 0; r < 16; ++r) {
    const int row = (r & 3) + 8 * (r >> 2) + 4 * lh;
    pacc[((size_t)bid * 32 + row) * 256 + w * 32 + q_] = acc[r];
  }
}

// ---------------- split-K merge: combine 2 partials -> f16 attn ----------------
__global__ __launch_bounds__(256) void k_merge(const float* __restrict__ pacc,
                                               const float* __restrict__ pml,
                                               f16* __restrict__ attnF) {
  const int inner = blockIdx.x;
  const int bh = inner & 7, qt = inner >> 3;
  const int b = bh >> 2, h = bh & 3;
  const int t = threadIdx.x;
  const int q = t >> 3, dgrp = t & 7;
  const float* a0 = pacc + ((size_t)inner * 32 + q) * 256 + dgrp * 32;
  const float* a1 = pacc + ((size_t)(inner + 512) * 32 + q) * 256 + dgrp * 32;
  const float m0 = pml[(size_t)inner * 64 + q];
  const float l0 = pml[(size_t)inner * 64 + 32 + q];
  const float m1 = pml[(size_t)(inner + 512) * 64 + q];
  const float l1 = pml[(size_t)(inner + 512) * 64 + 32 + q];
  const float m = fmaxf(m0, m1);
  const float e0 = __expf(m0 - m), e1 = __expf(m1 - m);
  const float linv = 1.f / (l0 * e0 + l1 * e1);
  const float c0 = e0 * linv, c1 = e1 * linv;
  f16* dst = attnF + ((size_t)b * S_ + qt * 32 + q) * D_ + h * DK_ + dgrp * 32;
#pragma unroll
  for (int i = 0; i < 4; ++i) {
    float4 x0 = ((const float4*)a0)[2 * i];
    float4 y0 = ((const float4*)a0)[2 * i + 1];
    float4 x1 = ((const float4*)a1)[2 * i];
    float4 y1 = ((const float4*)a1)[2 * i + 1];
    f16x8 o = {(f16)(x0.x * c0 + x1.x * c1), (f16)(x0.y * c0 + x1.y * c1),
               (f16)(x0.z * c0 + x1.z * c1), (f16)(x0.w * c0 + x1.w * c1),
               (f16)(y0.x * c0 + y1.x * c1), (f16)(y0.y * c0 + y1.y * c1),
               (f16)(y0.z * c0 + y1.z * c1), (f16)(y0.w * c0 + y1.w * c1)};
    *(f16x8*)(dst + 8 * i) = o;
  }
}

// ---------------- output projection: LDS-staged f16 MFMA GEMM ----------------
__global__ __launch_bounds__(256, 1) void k_wo(const f16* __restrict__ A,
                                               const f16* __restrict__ Wt,
                                               const float* __restrict__ bias,
                                               float* __restrict__ C) {
  __shared__ __align__(16) f16 Abuf[2][128 * 64];
  __shared__ __align__(16) f16 Bbuf[2][128 * 64];
  const int t = threadIdx.x;
  const int w = t >> 6, lane = t & 63;
  const int wr = w >> 1, wc = w & 1;
  const int brow = blockIdx.y * 128, bcol = blockIdx.x * 128;

  int srow[4], skof[4];
#pragma unroll
  for (int u = 0; u < 4; ++u) {
    int c = t + 256 * u;
    int sub = c >> 6, l6 = c & 63;
    srow[u] = (sub >> 2) * 32 + (l6 & 31);
    skof[u] = (sub & 3) * 16 + (l6 >> 5) * 8;
  }

  uint4 ra0, ra1, ra2, ra3, rb0, rb1, rb2, rb3;
#define LOAD_TILE(K0)                                                        \
  {                                                                          \
    ra0 = *(const uint4*)(A + (size_t)(brow + srow[0]) * D_ + (K0) + skof[0]); \
    ra1 = *(const uint4*)(A + (size_t)(brow + srow[1]) * D_ + (K0) + skof[1]); \
    ra2 = *(const uint4*)(A + (size_t)(brow + srow[2]) * D_ + (K0) + skof[2]); \
    ra3 = *(const uint4*)(A + (size_t)(brow + srow[3]) * D_ + (K0) + skof[3]); \
    rb0 = *(const uint4*)(Wt + (size_t)(bcol + srow[0]) * D_ + (K0) + skof[0]); \
    rb1 = *(const uint4*)(Wt + (size_t)(bcol + srow[1]) * D_ + (K0) + skof[1]); \
    rb2 = *(const uint4*)(Wt + (size_t)(bcol + srow[2]) * D_ + (K0) + skof[2]); \
    rb3 = *(const uint4*)(Wt + (size_t)(bcol + srow[3]) * D_ + (K0) + skof[3]); \
  }
#define WRITE_TILE(BUF)                                       \
  {                                                           \
    *(uint4*)&Abuf[BUF][(t + 0) * 8] = ra0;                   \
    *(uint4*)&Abuf[BUF][(t + 256) * 8] = ra1;                 \
    *(uint4*)&Abuf[BUF][(t + 512) * 8] = ra2;                 \
    *(uint4*)&Abuf[BUF][(t + 768) * 8] = ra3;                 \
    *(uint4*)&Bbuf[BUF][(t + 0) * 8] = rb0;                   \
    *(uint4*)&Bbuf[BUF][(t + 256) * 8] = rb1;                 \
    *(uint4*)&Bbuf[BUF][(t + 512) * 8] = rb2;                 \
    *(uint4*)&Bbuf[BUF][(t + 768) * 8] = rb3;                 \
  }

  f32x16 acc00{}, acc01{}, acc10{}, acc11{};

  LOAD_TILE(0);
  WRITE_TILE(0);
  LOAD_TILE(64);
  __syncthreads();

  int cur = 0;
  for (int kt = 0; kt < 16; ++kt) {
    const int am0 = (wr * 2 + 0) * 4, am1 = (wr * 2 + 1) * 4;
    const int bn0 = (wc * 2 + 0) * 4, bn1 = (wc * 2 + 1) * 4;
#pragma unroll
    for (int kk = 0; kk < 4; ++kk) {
      f16x8 a0 = *(const f16x8*)&Abuf[cur][(am0 + kk) * 512 + lane * 8];
      f16x8 a1 = *(const f16x8*)&Abuf[cur][(am1 + kk) * 512 + lane * 8];
      f16x8 b0 = *(const f16x8*)&Bbuf[cur][(bn0 + kk) * 512 + lane * 8];
      f16x8 b1 = *(const f16x8*)&Bbuf[cur][(bn1 + kk) * 512 + lane * 8];
      acc00 = __builtin_amdgcn_mfma_f32_32x32x16_f16(a0, b0, acc00, 0, 0, 0);
      acc01 = __builtin_amdgcn_mfma_f32_32x32x16_f16(a0, b1, acc01, 0, 0, 0);
      acc10 = __builtin_amdgcn_mfma_f32_32x32x16_f16(a1, b0, acc10, 0, 0, 0);
      acc11 = __builtin_amdgcn_mfma_f32_32x32x16_f16(a1, b1, acc11, 0, 0, 0);
    }
    if (kt + 1 < 16) {
      WRITE_TILE(cur ^ 1);
      if (kt + 2 < 16) LOAD_TILE((kt + 2) * 64);
    }
    __syncthreads();
    cur ^= 1;
  }

  const int l31 = lane & 31, lh = lane >> 5;
  const float bv0 = bias[bcol + (wc * 2 + 0) * 32 + l31];
  const float bv1 = bias[bcol + (wc * 2 + 1) * 32 + l31];
#pragma unroll
  for (int r = 0; r < 16; ++r) {
    const int row = (r & 3) + 8 * (r >> 2) + 4 * lh;
    const size_t m0r = (size_t)(brow + (wr * 2 + 0) * 32 + row) * D_;
    const size_t m1r = (size_t)(brow + (wr * 2 + 1) * 32 + row) * D_;
    C[m0r + bcol + (wc * 2 + 0) * 32 + l31] = acc00[r] + bv0;
    C[m0r + bcol + (wc * 2 + 1) * 32 + l31] = acc01[r] + bv1;
    C[m1r + bcol + (wc * 2 + 0) * 32 + l31] = acc10[r] + bv0;
    C[m1r + bcol + (wc * 2 + 1) * 32 + l31] = acc11[r] + bv1;
  }
#undef LOAD_TILE
#undef WRITE_TILE
}

extern "C" void kernel_launch(void* const* d_in, const int* in_sizes, int n_in,
                              void* d_out, int out_size, void* d_ws, size_t ws_size,
                              hipStream_t stream) {
  const float* Q_input = (const float*)d_in[0];
  const float* K = (const float*)d_in[1];
  const float* V = (const float*)d_in[2];
  const float* Wq_w = (const float*)d_in[4];
  const float* Wq_b = (const float*)d_in[5];
  const float* Wo_w = (const float*)d_in[6];
  const float* Wo_b = (const float*)d_in[7];
  const float* proj_w = (const float*)d_in[8];
  const float* proj_b = (const float*)d_in[9];
  const float* geo_w = (const float*)d_in[10];
  const float* temp = (const float*)d_in[11];

  float* ws = (float*)d_ws;
  float* cbias = ws;                       // 128
  float* pbias = cbias + 128;              // 128
  f16* Mf = (f16*)(pbias + 128);           // 98304 f16
  f16* Mkf = Mf + 98304;                   // 98304 f16
  float* qn2 = (float*)(Mkf + 98304);      // 16384
  float* kn2 = qn2 + 16384;                // 16384
  f16* pqF = (f16*)(kn2 + 16384);          // 262144 f16
  f16* pkF = pqF + 262144;                 // 262144 f16
  f16* Vt2 = pkF + 262144;                 // 2097152 f16
  f16* attnF = Vt2 + 2097152;              // 4194304 f16 (B*S*D)
  f16* Wf = attnF + 4194304;               // 1048576 f16
  float* pacc = (float*)(Wf + 1048576);    // 8388608 f32
  float* pml = pacc + 8388608;             // 65536 f32
  float* out = (float*)d_out;

  k_fuse<<<dim3(384), dim3(256), 0, stream>>>(Wq_w, proj_w, Mf);
  k_fuse_bias<<<dim3(1), dim3(128), 0, stream>>>(Wq_b, proj_w, proj_b, cbias, pbias);
  k_expand<<<dim3(384), dim3(256), 0, stream>>>(proj_w, Mkf);
  k_wcvt<<<dim3(512), dim3(256), 0, stream>>>(Wo_w, Wf);
  k_vt<<<dim3(32, 4, 8), dim3(256), 0, stream>>>(V, Vt2);
  k_gen<<<dim3(256), dim3(256), 0, stream>>>(Q_input, K, Mf, Mkf, cbias, pbias,
                                             pqF, qn2, pkF, kn2);
  k_attn<<<dim3(1024), dim3(512), 0, stream>>>(pqF, qn2, pkF, kn2, Vt2, geo_w,
                                               temp, pacc, pml);
  k_merge<<<dim3(512), dim3(256), 0, stream>>>(pacc, pml, attnF);
  k_wo<<<dim3(8, 32), dim3(256), 0, stream>>>(attnF, Wf, Wo_b, out);
}

// Round 17
// 140.230 us; speedup vs baseline: 1.4947x; 1.0127x over previous
//
#include <hip/hip_runtime.h>
#include <hip/hip_bf16.h>
#include <math.h>

#define B_ 2
#define S_ 2048
#define D_ 1024
#define H_ 4
#define DK_ 256
#define NJ 24
#define NG 96
#define KTA 128
#define NT2 (S_ / KTA)
#define NTL (NT2 / 2)

typedef _Float16 f16;
typedef _Float16 f16x2 __attribute__((ext_vector_type(2)));
typedef _Float16 f16x4 __attribute__((ext_vector_type(4)));
typedef _Float16 f16x8 __attribute__((ext_vector_type(8)));
typedef float f32x16 __attribute__((ext_vector_type(16)));
typedef float v2f __attribute__((ext_vector_type(2)));

// ---------------- fold Wq into proj -> f16 Mf[hj][d] ----------------
__global__ __launch_bounds__(256) void k_fuse(const float* __restrict__ Wq_w,
                                              const float* __restrict__ proj_w,
                                              f16* __restrict__ Mf) {
  int tid = blockIdx.x * 256 + threadIdx.x;
  int hj = tid >> 10;
  int d = tid & 1023;
  int h = hj / NJ, j = hj - h * NJ;
  const float* wq = Wq_w + (size_t)(h * DK_) * D_ + d;
  const float* pw = proj_w + j * DK_;
  float acc = 0.f;
#pragma unroll 8
  for (int k = 0; k < DK_; ++k) acc += wq[(size_t)k * D_] * pw[k];
  Mf[(size_t)hj * D_ + d] = (f16)acc;
}

__global__ void k_fuse_bias(const float* __restrict__ Wq_b,
                            const float* __restrict__ proj_w,
                            const float* __restrict__ proj_b,
                            float* __restrict__ cbias,
                            float* __restrict__ pbias) {
  int hj = threadIdx.x;
  if (hj < NG) {
    int h = hj / NJ, j = hj - h * NJ;
    float acc = proj_b[j];
    for (int k = 0; k < DK_; ++k) acc += Wq_b[h * DK_ + k] * proj_w[j * DK_ + k];
    cbias[hj] = acc;
    pbias[hj] = proj_b[j];
  }
}

// ---------------- expand proj_w to block-diagonal f16 Mkf[96][1024] ----------------
__global__ __launch_bounds__(256) void k_expand(const float* __restrict__ proj_w,
                                                f16* __restrict__ Mkf) {
  int tid = blockIdx.x * 256 + threadIdx.x;  // 98304
  int hj = tid >> 10, d = tid & 1023;
  int h = hj / NJ, j = hj - h * NJ;
  float v = ((d >> 8) == h) ? proj_w[j * DK_ + (d & 255)] : 0.f;
  Mkf[tid] = (f16)v;
}

// ---------------- W -> f16 convert ----------------
__global__ __launch_bounds__(256) void k_wcvt(const float* __restrict__ W,
                                              f16* __restrict__ Wt) {
  int i = (blockIdx.x * 256 + threadIdx.x) * 8;
  float4 a = *(const float4*)(W + i);
  float4 b = *(const float4*)(W + i + 4);
  f16x8 o = {(f16)a.x, (f16)a.y, (f16)a.z, (f16)a.w,
             (f16)b.x, (f16)b.y, (f16)b.z, (f16)b.w};
  *(f16x8*)(Wt + i) = o;
}

// ---------------- V transpose + f16 -> blocked layout ----------------
__global__ __launch_bounds__(256) void k_vt(const float* __restrict__ V,
                                            f16* __restrict__ Vt2) {
  __shared__ f16 tile[64][72];
  int t = threadIdx.x;
  int s0 = blockIdx.x * 64, c0 = blockIdx.y * 64;
  int bh = blockIdx.z;
  int b = bh >> 2, h = bh & 3;
  const float* src = V + (size_t)b * S_ * D_ + h * DK_ + c0;
#pragma unroll
  for (int u = 0; u < 4; ++u) {
    int row = (t >> 4) + 16 * u;
    int c4 = (t & 15) * 4;
    float4 v = *(const float4*)(src + (size_t)(s0 + row) * D_ + c4);
    tile[c4 + 0][row] = (f16)v.x;
    tile[c4 + 1][row] = (f16)v.y;
    tile[c4 + 2][row] = (f16)v.z;
    tile[c4 + 3][row] = (f16)v.w;
  }
  __syncthreads();
#pragma unroll
  for (int u = 0; u < 2; ++u) {
    int sid = t + 256 * u;
    int sgroup = sid & 7, dkl = sid >> 3;
    int dk = c0 + dkl, s = s0 + sgroup * 8;
    int wv = dk >> 5, qq = dk & 31;
    int kt = s >> 7, ks = (s >> 4) & 7, lhh = (s >> 3) & 1;
    size_t idx = ((((size_t)(bh * 8 + wv) * 16 + kt) * 8 + ks) * 2 + lhh) * 256 + qq * 8;
    *(f16x8*)(Vt2 + idx) = *(const f16x8*)&tile[dkl][sgroup * 8];
  }
}

// ---------------- unified gen via f16 MFMA + psi ----------------
__global__ __launch_bounds__(256, 1) void k_gen(
    const float* __restrict__ Q, const float* __restrict__ Kin,
    const f16* __restrict__ Mf, const f16* __restrict__ Mkf,
    const float* __restrict__ cbias, const float* __restrict__ pbias,
    f16* __restrict__ pqF, float* __restrict__ qn2,
    f16* __restrict__ pkF, float* __restrict__ kn2) {
  __shared__ __align__(16) f16 Xs[8192];
  __shared__ __align__(16) f16 Bs[24576];
  __shared__ __align__(16) float redP[4][32][96];
  __shared__ float genL[32][100];

  const int t = threadIdx.x;
  const int w = t >> 6, lane = t & 63;
  const int l31 = lane & 31, lh = lane >> 5;
  const bool isQ = blockIdx.x < 128;
  const int r0 = (isQ ? blockIdx.x : blockIdx.x - 128) * 32;
  const float* X = isQ ? Q : Kin;
  const f16* Bf = isQ ? Mf : Mkf;
  const float* bias = isQ ? cbias : pbias;

  int xrow[8], xk4[8];
#pragma unroll
  for (int u = 0; u < 8; ++u) {
    int idx = t + 256 * u;
    xrow[u] = idx >> 6;
    xk4[u] = idx & 63;
  }
  int bcol[12], bkg[12];
#pragma unroll
  for (int u = 0; u < 12; ++u) {
    int idx = t + 256 * u;
    bcol[u] = idx >> 5;
    bkg[u] = idx & 31;
  }

  float4 xr[8];
  f16x8 br[12];
#define XLOAD(K0)                                                              \
  {                                                                            \
    _Pragma("unroll") for (int u = 0; u < 8; ++u) xr[u] =                      \
        *(const float4*)(X + (size_t)(r0 + xrow[u]) * D_ + (K0) + xk4[u] * 4); \
  }
#define BLOAD(K0)                                                            \
  {                                                                          \
    _Pragma("unroll") for (int u = 0; u < 12; ++u) br[u] =                   \
        *(const f16x8*)(Bf + (size_t)bcol[u] * D_ + (K0) + bkg[u] * 8);      \
  }
#define XWRITE()                                                            \
  {                                                                         \
    _Pragma("unroll") for (int u = 0; u < 8; ++u) {                         \
      f16x4 v = {(f16)xr[u].x, (f16)xr[u].y, (f16)xr[u].z, (f16)xr[u].w};   \
      *(f16x4*)&Xs[((xk4[u] >> 1) * 32 + xrow[u]) * 8 + (xk4[u] & 1) * 4] = v; \
    }                                                                       \
  }
#define BWRITE()                                                            \
  {                                                                         \
    _Pragma("unroll") for (int u = 0; u < 12; ++u)                          \
        *(f16x8*)&Bs[(bcol[u] >> 5) * 8192 + bkg[u] * 256 +                 \
                     (bcol[u] & 31) * 8] = br[u];                           \
  }

  XLOAD(0);
  BLOAD(0);
  XWRITE();
  BWRITE();
  __syncthreads();

  f32x16 acc0{}, acc1{}, acc2{};
  for (int ch = 0; ch < 4; ++ch) {
    if (ch < 3) {
      XLOAD((ch + 1) * 256);
      BLOAD((ch + 1) * 256);
    }
#pragma unroll
    for (int i = 0; i < 4; ++i) {
      const int kk = w * 4 + i;
      const int off = (kk * 2 + lh) * 256 + l31 * 8;
      f16x8 af = *(const f16x8*)&Xs[off];
      f16x8 b0 = *(const f16x8*)&Bs[off];
      f16x8 b1 = *(const f16x8*)&Bs[8192 + off];
      f16x8 b2 = *(const f16x8*)&Bs[16384 + off];
      acc0 = __builtin_amdgcn_mfma_f32_32x32x16_f16(af, b0, acc0, 0, 0, 0);
      acc1 = __builtin_amdgcn_mfma_f32_32x32x16_f16(af, b1, acc1, 0, 0, 0);
      acc2 = __builtin_amdgcn_mfma_f32_32x32x16_f16(af, b2, acc2, 0, 0, 0);
    }
    __syncthreads();
    if (ch < 3) {
      XWRITE();
      BWRITE();
      __syncthreads();
    }
  }
#undef XLOAD
#undef BLOAD
#undef XWRITE
#undef BWRITE

#pragma unroll
  for (int r = 0; r < 16; ++r) {
    const int row = (r & 3) + 8 * (r >> 2) + 4 * lh;
    redP[w][row][l31] = acc0[r];
    redP[w][row][32 + l31] = acc1[r];
    redP[w][row][64 + l31] = acc2[r];
  }
  __syncthreads();

  {
    const int row = t >> 3, cg = t & 7;
#pragma unroll
    for (int c = 0; c < 12; ++c) {
      int col = cg * 12 + c;
      genL[row][col] = redP[0][row][col] + redP[1][row][col] +
                       redP[2][row][col] + redP[3][row][col] + bias[col];
    }
  }
  __syncthreads();

  {
    const int rg = t >> 6;
    const int hh = (t & 63) >> 4;
    const int ii = t & 15;
    const int j = ii & 7;
    f16* po = isQ ? pqF : pkF;
    float* n2o = isQ ? qn2 : kn2;
#pragma unroll 2
    for (int r = 0; r < 8; ++r) {
      int row = rg * 8 + r;
      int g = r0 + row;
      int b = g >> 11, s = g & (S_ - 1);
      const float* gl = &genL[row][hh * NJ];
      float A = gl[j], Bg = gl[8 + j];
      float Th = fminf(fmaxf(gl[16 + j], -8.f), 8.f);
      float val = (ii < 8) ? (A * expf(Th) + Bg * cosf(Th)) : (Bg * sinf(Th));
      size_t base = (size_t)(b * H_ + hh) * S_ + s;
      po[base * 16 + ii] = (f16)val;
      float sq = val * val;
#pragma unroll
      for (int off = 1; off < 16; off <<= 1) sq += __shfl_xor(sq, off);
      if (ii == 0) n2o[base] = sq;
    }
  }
}

// ---------------- per-bh khmax: khm[bh] = sqrt(max_k kn2 + 1e-6) ----------------
__global__ __launch_bounds__(256) void k_kmax(const float* __restrict__ kn2,
                                              float* __restrict__ khm) {
  __shared__ float red[4];
  const int bh = blockIdx.x, t = threadIdx.x;
  float m = 0.f;
#pragma unroll
  for (int u = 0; u < 8; ++u) m = fmaxf(m, kn2[(size_t)bh * S_ + t + 256 * u]);
#pragma unroll
  for (int off = 1; off < 64; off <<= 1) m = fmaxf(m, __shfl_xor(m, off));
  if ((t & 63) == 0) red[t >> 6] = m;
  __syncthreads();
  if (t == 0) {
    float mm = fmaxf(fmaxf(red[0], red[1]), fmaxf(red[2], red[3]));
    khm[bh] = sqrtf(mm + 1e-6f);
  }
}

// ---------------- MFMA flash geometric attention, static-max softmax ----------------
// Split-K x2, 1 barrier per 128-k tile (Plds + kn2s double-buffered).
// p = exp(sv - Mhat), Mhat = sumg*qh*khmax - 3 (upper bound by Cauchy-Schwarz,
// -3 keeps p in good f16 range; common factor cancels in normalization).
__global__ __launch_bounds__(512, 4) void k_attn(
    const f16* __restrict__ pqF, const float* __restrict__ qn2,
    const f16* __restrict__ pkF, const float* __restrict__ kn2,
    const f16* __restrict__ Vt2, const float* __restrict__ geo_w,
    const float* __restrict__ temp, const float* __restrict__ khm,
    float* __restrict__ pacc, float* __restrict__ pml) {
  __shared__ __align__(16) float kn2s[2][KTA];
  __shared__ __align__(16) float khs[2][KTA];
  __shared__ float sPart[8][32];
  __shared__ __align__(16) f16 Plds[2][16][32][8];

  const int t = threadIdx.x;
  const int w = t >> 6;
  const int lane = t & 63;
  const int q_ = lane & 31;
  const int lh = lane >> 5;

  const int bid = blockIdx.x;
  const int half = bid >> 9;
  const int inner = bid & 511;
  const int bh = inner & 7, qt = inner >> 3;
  const int q0 = qt * 32;
  const int kofs = half * (S_ / 2);

  const size_t bhS = (size_t)bh * S_;
  const f16* pkb = pkF + bhS * 16;
  const float* kn2b = kn2 + bhS + kofs;

  const float scale = 0.25f / temp[0];
  const float g0s = geo_w[0] * scale, g1s = geo_w[1] * scale, g2s = geo_w[2] * scale;
  const float g3s = geo_w[3] * scale;

  const f16x8 bq = *(const f16x8*)(pqF + (bhS + q0 + q_) * 16 + lh * 8);
  const float qn2q = qn2[bhS + q0 + q_];
  const float qh = sqrtf(qn2q + 1e-6f);
  const float qh3 = qh * g3s;
  const float sumg = fabsf(g0s) + fabsf(g1s) + fabsf(g2s) + fabsf(g3s);
  const float Mhat = sumg * qh * khm[bh] - 3.0f;

  const v2f qn2v = {qn2q, qn2q};
  const v2f g0v = {g0s, g0s}, g1v = {g1s, g1s}, g2v = {g2s, g2s};
  const v2f zero2 = {0.f, 0.f}, eps2 = {1e-6f, 1e-6f};
  const v2f mhv = {Mhat, Mhat};

  const f16* ap_base = pkb + (size_t)(kofs + w * 16 + (q_ & 15)) * 16 +
                       ((q_ < 16) ? lh * 8 : (1 - lh) * 8);
  const f16* vb_lane = Vt2 + ((size_t)(bh * 8 + w) * 16 + half * NTL) * 4096 +
                       lh * 256 + q_ * 8;

  if (t < KTA) { float kv = kn2b[t]; kn2s[0][t] = kv; khs[0][t] = sqrtf(kv + 1e-6f); }
  float lreg = 0.f;
  f32x16 acc{};
  const f32x16 zacc{};

  f16x8 af = *(const f16x8*)ap_base;
  f16x8 bv[8];
#pragma unroll
  for (int ks = 0; ks < 8; ++ks) bv[ks] = *(const f16x8*)(vb_lane + ks * 512);
  __syncthreads();

  for (int ktl = 0; ktl < NTL; ++ktl) {
    const int k0l = ktl * KTA;
    const int cb = ktl & 1, nb = cb ^ 1;

    float knv = 0.f;
    if (t < KTA && ktl + 1 < NTL) knv = kn2b[k0l + KTA + t];

    f16x8 afx = af;
    if (q_ >= 16 && lh == 1) afx = -afx;
    __builtin_amdgcn_s_setprio(1);
    f32x16 sc = __builtin_amdgcn_mfma_f32_32x32x16_f16(afx, bq, zacc, 0, 0, 0);
    __builtin_amdgcn_s_setprio(0);
    if (ktl + 1 < NTL) af = *(const f16x8*)(ap_base + (size_t)(k0l + KTA) * 16);

    // sv + p (static reference Mhat; no cross-wave reduction needed)
    float pv[8];
    v2f psv = {0.f, 0.f};
#pragma unroll
    for (int rp = 0; rp < 4; ++rp) {
      const int r = 2 * rp;
      const int kb2 = w * 16 + 4 * lh + (rp & 1) * 2 + (rp >> 1) * 8;
      v2f tn = {sc[r], sc[r + 1]};
      v2f sp = {sc[r + 8], sc[r + 9]};
      v2f kn2p = *(const v2f*)&kn2s[cb][kb2];
      v2f khp = *(const v2f*)&khs[cb][kb2];
      v2f wr = qn2v * kn2p - tn * tn - sp * sp;
      wr = __builtin_elementwise_max(wr, zero2) + eps2;
      v2f wg = {sqrtf(wr.x), sqrtf(wr.y)};
      v2f sv2 = g0v * wg + g1v * tn + g2v * sp + qh3 * khp - mhv;
      v2f p2 = {__expf(sv2.x), __expf(sv2.y)};
      pv[r] = p2.x;
      pv[r + 1] = p2.y;
      psv += p2;
    }
    lreg += psv.x + psv.y;

    // stage next-tile kn2 into the other buffer (write precedes the barrier)
    if (t < KTA && ktl + 1 < NTL) {
      kn2s[nb][t] = knv;
      khs[nb][t] = sqrtf(knv + 1e-6f);
    }
    {
      f16x2 p01 = {(f16)pv[0], (f16)pv[1]};
      f16x2 p23 = {(f16)pv[2], (f16)pv[3]};
      f16x2 p45 = {(f16)pv[4], (f16)pv[5]};
      f16x2 p67 = {(f16)pv[6], (f16)pv[7]};
      *(f16x2*)&Plds[cb][2 * w + 0][q_][4 * lh + 0] = p01;
      *(f16x2*)&Plds[cb][2 * w + 0][q_][4 * lh + 2] = p23;
      *(f16x2*)&Plds[cb][2 * w + 1][q_][4 * lh + 0] = p45;
      *(f16x2*)&Plds[cb][2 * w + 1][q_][4 * lh + 2] = p67;
    }
    __syncthreads();  // single barrier per tile

    // ---- PV (no rescale: static reference) ----
    __builtin_amdgcn_s_setprio(1);
#pragma unroll
    for (int ks = 0; ks < 8; ++ks) {
      f16x8 pa = *(const f16x8*)&Plds[cb][2 * ks + lh][q_][0];
      acc = __builtin_amdgcn_mfma_f32_32x32x16_f16(pa, bv[ks], acc, 0, 0, 0);
    }
    __builtin_amdgcn_s_setprio(0);
    if (ktl + 1 < NTL) {
      const f16* vbn = vb_lane + (size_t)(ktl + 1) * 4096;
#pragma unroll
      for (int ks = 0; ks < 8; ++ks) bv[ks] = *(const f16x8*)(vbn + ks * 512);
    }
  }

  // ---- final l reduction + partial writes ----
  lreg += __shfl_xor(lreg, 32);
  if (lh == 0) sPart[w][q_] = lreg;
  __syncthreads();
  if (t < 32) {
    float s8 = 0.f;
#pragma unroll
    for (int i = 0; i < 8; ++i) s8 += sPart[i][t];
    pml[(size_t)bid * 64 + t] = s8;
  }
#pragma unroll
  for (int r = 0; r < 16; ++r) {
    const int row = (r & 3) + 8 * (r >> 2) + 4 * lh;
    pacc[((size_t)bid * 32 + row) * 256 + w * 32 + q_] = acc[r];
  }
}

// ---------------- split-K merge: (a0+a1)/(l0+l1) -> f16 attn ----------------
__global__ __launch_bounds__(256) void k_merge(const float* __restrict__ pacc,
                                               const float* __restrict__ pml,
                                               f16* __restrict__ attnF) {
  const int inner = blockIdx.x;
  const int bh = inner & 7, qt = inner >> 3;
  const int b = bh >> 2, h = bh & 3;
  const int t = threadIdx.x;
  const int q = t >> 3, dgrp = t & 7;
  const float* a0 = pacc + ((size_t)inner * 32 + q) * 256 + dgrp * 32;
  const float* a1 = pacc + ((size_t)(inner + 512) * 32 + q) * 256 + dgrp * 32;
  const float l0 = pml[(size_t)inner * 64 + q];
  const float l1 = pml[(size_t)(inner + 512) * 64 + q];
  const float linv = 1.f / (l0 + l1);
  f16* dst = attnF + ((size_t)b * S_ + qt * 32 + q) * D_ + h * DK_ + dgrp * 32;
#pragma unroll
  for (int i = 0; i < 4; ++i) {
    float4 x0 = ((const float4*)a0)[2 * i];
    float4 y0 = ((const float4*)a0)[2 * i + 1];
    float4 x1 = ((const float4*)a1)[2 * i];
    float4 y1 = ((const float4*)a1)[2 * i + 1];
    f16x8 o = {(f16)((x0.x + x1.x) * linv), (f16)((x0.y + x1.y) * linv),
               (f16)((x0.z + x1.z) * linv), (f16)((x0.w + x1.w) * linv),
               (f16)((y0.x + y1.x) * linv), (f16)((y0.y + y1.y) * linv),
               (f16)((y0.z + y1.z) * linv), (f16)((y0.w + y1.w) * linv)};
    *(f16x8*)(dst + 8 * i) = o;
  }
}

// ---------------- output projection: LDS-staged f16 MFMA GEMM ----------------
__global__ __launch_bounds__(256, 1) void k_wo(const f16* __restrict__ A,
                                               const f16* __restrict__ Wt,
                                               const float* __restrict__ bias,
                                               float* __restrict__ C) {
  __shared__ __align__(16) f16 Abuf[2][128 * 64];
  __shared__ __align__(16) f16 Bbuf[2][128 * 64];
  const int t = threadIdx.x;
  const int w = t >> 6, lane = t & 63;
  const int wr = w >> 1, wc = w & 1;
  const int brow = blockIdx.y * 128, bcol = blockIdx.x * 128;

  int srow[4], skof[4];
#pragma unroll
  for (int u = 0; u < 4; ++u) {
    int c = t + 256 * u;
    int sub = c >> 6, l6 = c & 63;
    srow[u] = (sub >> 2) * 32 + (l6 & 31);
    skof[u] = (sub & 3) * 16 + (l6 >> 5) * 8;
  }

  uint4 ra0, ra1, ra2, ra3, rb0, rb1, rb2, rb3;
#define LOAD_TILE(K0)                                                        \
  {                                                                          \
    ra0 = *(const uint4*)(A + (size_t)(brow + srow[0]) * D_ + (K0) + skof[0]); \
    ra1 = *(const uint4*)(A + (size_t)(brow + srow[1]) * D_ + (K0) + skof[1]); \
    ra2 = *(const uint4*)(A + (size_t)(brow + srow[2]) * D_ + (K0) + skof[2]); \
    ra3 = *(const uint4*)(A + (size_t)(brow + srow[3]) * D_ + (K0) + skof[3]); \
    rb0 = *(const uint4*)(Wt + (size_t)(bcol + srow[0]) * D_ + (K0) + skof[0]); \
    rb1 = *(const uint4*)(Wt + (size_t)(bcol + srow[1]) * D_ + (K0) + skof[1]); \
    rb2 = *(const uint4*)(Wt + (size_t)(bcol + srow[2]) * D_ + (K0) + skof[2]); \
    rb3 = *(const uint4*)(Wt + (size_t)(bcol + srow[3]) * D_ + (K0) + skof[3]); \
  }
#define WRITE_TILE(BUF)                                       \
  {                                                           \
    *(uint4*)&Abuf[BUF][(t + 0) * 8] = ra0;                   \
    *(uint4*)&Abuf[BUF][(t + 256) * 8] = ra1;                 \
    *(uint4*)&Abuf[BUF][(t + 512) * 8] = ra2;                 \
    *(uint4*)&Abuf[BUF][(t + 768) * 8] = ra3;                 \
    *(uint4*)&Bbuf[BUF][(t + 0) * 8] = rb0;                   \
    *(uint4*)&Bbuf[BUF][(t + 256) * 8] = rb1;                 \
    *(uint4*)&Bbuf[BUF][(t + 512) * 8] = rb2;                 \
    *(uint4*)&Bbuf[BUF][(t + 768) * 8] = rb3;                 \
  }

  f32x16 acc00{}, acc01{}, acc10{}, acc11{};

  LOAD_TILE(0);
  WRITE_TILE(0);
  LOAD_TILE(64);
  __syncthreads();

  int cur = 0;
  for (int kt = 0; kt < 16; ++kt) {
    const int am0 = (wr * 2 + 0) * 4, am1 = (wr * 2 + 1) * 4;
    const int bn0 = (wc * 2 + 0) * 4, bn1 = (wc * 2 + 1) * 4;
#pragma unroll
    for (int kk = 0; kk < 4; ++kk) {
      f16x8 a0 = *(const f16x8*)&Abuf[cur][(am0 + kk) * 512 + lane * 8];
      f16x8 a1 = *(const f16x8*)&Abuf[cur][(am1 + kk) * 512 + lane * 8];
      f16x8 b0 = *(const f16x8*)&Bbuf[cur][(bn0 + kk) * 512 + lane * 8];
      f16x8 b1 = *(const f16x8*)&Bbuf[cur][(bn1 + kk) * 512 + lane * 8];
      acc00 = __builtin_amdgcn_mfma_f32_32x32x16_f16(a0, b0, acc00, 0, 0, 0);
      acc01 = __builtin_amdgcn_mfma_f32_32x32x16_f16(a0, b1, acc01, 0, 0, 0);
      acc10 = __builtin_amdgcn_mfma_f32_32x32x16_f16(a1, b0, acc10, 0, 0, 0);
      acc11 = __builtin_amdgcn_mfma_f32_32x32x16_f16(a1, b1, acc11, 0, 0, 0);
    }
    if (kt + 1 < 16) {
      WRITE_TILE(cur ^ 1);
      if (kt + 2 < 16) LOAD_TILE((kt + 2) * 64);
    }
    __syncthreads();
    cur ^= 1;
  }

  const int l31 = lane & 31, lh = lane >> 5;
  const float bv0 = bias[bcol + (wc * 2 + 0) * 32 + l31];
  const float bv1 = bias[bcol + (wc * 2 + 1) * 32 + l31];
#pragma unroll
  for (int r = 0; r < 16; ++r) {
    const int row = (r & 3) + 8 * (r >> 2) + 4 * lh;
    const size_t m0r = (size_t)(brow + (wr * 2 + 0) * 32 + row) * D_;
    const size_t m1r = (size_t)(brow + (wr * 2 + 1) * 32 + row) * D_;
    C[m0r + bcol + (wc * 2 + 0) * 32 + l31] = acc00[r] + bv0;
    C[m0r + bcol + (wc * 2 + 1) * 32 + l31] = acc01[r] + bv1;
    C[m1r + bcol + (wc * 2 + 0) * 32 + l31] = acc10[r] + bv0;
    C[m1r + bcol + (wc * 2 + 1) * 32 + l31] = acc11[r] + bv1;
  }
#undef LOAD_TILE
#undef WRITE_TILE
}

extern "C" void kernel_launch(void* const* d_in, const int* in_sizes, int n_in,
                              void* d_out, int out_size, void* d_ws, size_t ws_size,
                              hipStream_t stream) {
  const float* Q_input = (const float*)d_in[0];
  const float* K = (const float*)d_in[1];
  const float* V = (const float*)d_in[2];
  const float* Wq_w = (const float*)d_in[4];
  const float* Wq_b = (const float*)d_in[5];
  const float* Wo_w = (const float*)d_in[6];
  const float* Wo_b = (const float*)d_in[7];
  const float* proj_w = (const float*)d_in[8];
  const float* proj_b = (const float*)d_in[9];
  const float* geo_w = (const float*)d_in[10];
  const float* temp = (const float*)d_in[11];

  float* ws = (float*)d_ws;
  float* cbias = ws;                       // 128
  float* pbias = cbias + 128;              // 128
  float* khm = pbias + 128;                // 128 (8 used)
  f16* Mf = (f16*)(khm + 128);             // 98304 f16
  f16* Mkf = Mf + 98304;                   // 98304 f16
  float* qn2 = (float*)(Mkf + 98304);      // 16384
  float* kn2 = qn2 + 16384;                // 16384
  f16* pqF = (f16*)(kn2 + 16384);          // 262144 f16
  f16* pkF = pqF + 262144;                 // 262144 f16
  f16* Vt2 = pkF + 262144;                 // 2097152 f16
  f16* attnF = Vt2 + 2097152;              // 4194304 f16 (B*S*D)
  f16* Wf = attnF + 4194304;               // 1048576 f16
  float* pacc = (float*)(Wf + 1048576);    // 8388608 f32
  float* pml = pacc + 8388608;             // 65536 f32
  float* out = (float*)d_out;

  k_fuse<<<dim3(384), dim3(256), 0, stream>>>(Wq_w, proj_w, Mf);
  k_fuse_bias<<<dim3(1), dim3(128), 0, stream>>>(Wq_b, proj_w, proj_b, cbias, pbias);
  k_expand<<<dim3(384), dim3(256), 0, stream>>>(proj_w, Mkf);
  k_wcvt<<<dim3(512), dim3(256), 0, stream>>>(Wo_w, Wf);
  k_vt<<<dim3(32, 4, 8), dim3(256), 0, stream>>>(V, Vt2);
  k_gen<<<dim3(256), dim3(256), 0, stream>>>(Q_input, K, Mf, Mkf, cbias, pbias,
                                             pqF, qn2, pkF, kn2);
  k_kmax<<<dim3(8), dim3(256), 0, stream>>>(kn2, khm);
  k_attn<<<dim3(1024), dim3(512), 0, stream>>>(pqF, qn2, pkF, kn2, Vt2, geo_w,
                                               temp, khm, pacc, pml);
  k_merge<<<dim3(512), dim3(256), 0, stream>>>(pacc, pml, attnF);
  k_wo<<<dim3(8, 32), dim3(256), 0, stream>>>(attnF, Wf, Wo_b, out);
}